// Round 9
// baseline (100.261 us; speedup 1.0000x reference)
//
#include <hip/hip_runtime.h>

// Disable FMA contraction so float rounding matches the numpy reference
// op-for-op (threshold compares at 0.5 and argmax ties depend on it).
#pragma clang fp contract(off)

#define BB 32     // batch
#define NN 100    // gt boxes per image
#define PP 8732   // priors
#define CH 16     // j-chunk for the transposed row-max reduce
#define LDW 257   // padded row stride (u32) -> 2-way banks only (free)
#define NBX 35    // blocks along the prior axis

// -------------------------------------------------------------------------
// Kernel 1: thread owns prior p of batch b.  (r1 geometry + forced ILP)
//   Cross-round finding: k_iou pinned at ~37us across 3 structures, with
//   VGPR=12-20 -> compiler schedules ONE j-chain at a time; ~65% of time
//   is exposed dependent-chain latency (load -> minmax -> 6-deep IEEE div
//   -> cmp), not issue. Fix: hand-interleave 4 independent j-chains per
//   iteration (4 scalar g loads up front, 4 independent IoU chains), and
//   give the allocator room with __launch_bounds__(256,2).
//  - area_a recomputed inline from g (identical expression/bits as the old
//    s_area fill) -- kills the per-j ds_read; inner loop = SMEM + VALU +
//    one ds_write.
//  - Column argmax: sequential strict-> updates in ascending j order after
//    the 4 chains -- bit-exact first-occurrence semantics.
//  - Row max: verified chunk-transpose (s_iou[16][257]), phase A = 16 rows
//    x 16 segs of 16 ascending-p cols, key = (iou<<32)|~p (max iou, min p),
//    phase B merges 16 segs -> part[b][bx][j] (USE_PART) or atomicMax.
//  - Out-of-range lanes compute the real IoU of prior PP-1: duplicate
//    columns tie with p=8731's value and lose the ~p min-p tie-break.
//  - Exact IEEE f32 division kept -> bit-identical decisions vs reference.
// -------------------------------------------------------------------------

__device__ __forceinline__ float iou_one(
    const float4 g, float px1, float py1, float px2, float py2, float area_b)
{
    float area_a = (g.z - g.x) * (g.w - g.y);   // same expr as old s_area
    float ltx = fmaxf(g.x, px1), lty = fmaxf(g.y, py1);
    float rbx = fminf(g.z, px2), rby = fminf(g.w, py2);
    float w = fmaxf(rbx - ltx, 0.0f), h = fmaxf(rby - lty, 0.0f);
    float inter = w * h;
    return inter / (area_a + area_b - inter + 1e-6f);
}

template <bool USE_PART>
__global__ __launch_bounds__(256, 2) void k_iou_pass(
    const float* __restrict__ gt,        // [B,N,4] xyxy
    const float* __restrict__ priors,    // [P,4] cxcywh
    unsigned long long* __restrict__ red,   // part [B][NBX][NN] or gkey [B][N]
    unsigned char* __restrict__ m8)         // [B,P]: best_j | (bg?0x80:0)
{
    __shared__ unsigned int s_iou[CH * LDW];          // 16.4 KB
    __shared__ unsigned long long s_part[NN][17];     // 13.6 KB

    const int b = blockIdx.y;
    const int t = threadIdx.x;
    const int p = blockIdx.x * 256 + t;
    const bool valid = p < PP;
    const int pc = valid ? p : (PP - 1);

    // wave-uniform base: compiler scalarizes these loads (s_load_dwordx4)
    const float4* __restrict__ gtb =
        reinterpret_cast<const float4*>(gt) + b * NN;

    const float4 pr = reinterpret_cast<const float4*>(priors)[pc];
    const float px1 = pr.x - pr.z * 0.5f;
    const float py1 = pr.y - pr.w * 0.5f;
    const float px2 = pr.x + pr.z * 0.5f;
    const float py2 = pr.y + pr.w * 0.5f;
    const float area_b = (px2 - px1) * (py2 - py1);

    float best_ov = -1.0f;
    int best_j = 0;

    for (int jc = 0; jc < NN; jc += CH) {
        const int nr = (NN - jc) < CH ? (NN - jc) : CH;   // 16,...,16,4

        // 4-way interleaved chains (nr is always a multiple of 4)
        for (int jj = 0; jj < nr; jj += 4) {
            const int j = jc + jj;
            float4 g0 = gtb[j + 0];              // uniform -> SGPR quads,
            float4 g1 = gtb[j + 1];              // batched s_loads
            float4 g2 = gtb[j + 2];
            float4 g3 = gtb[j + 3];
            float i0 = iou_one(g0, px1, py1, px2, py2, area_b);
            float i1 = iou_one(g1, px1, py1, px2, py2, area_b);
            float i2 = iou_one(g2, px1, py1, px2, py2, area_b);
            float i3 = iou_one(g3, px1, py1, px2, py2, area_b);
            // sequential ascending-j argmax: exact first-occurrence
            if (i0 > best_ov) { best_ov = i0; best_j = j + 0; }
            if (i1 > best_ov) { best_ov = i1; best_j = j + 1; }
            if (i2 > best_ov) { best_ov = i2; best_j = j + 2; }
            if (i3 > best_ov) { best_ov = i3; best_j = j + 3; }
            s_iou[(jj + 0) * LDW + t] = __float_as_uint(i0);
            s_iou[(jj + 1) * LDW + t] = __float_as_uint(i1);
            s_iou[(jj + 2) * LDW + t] = __float_as_uint(i2);
            s_iou[(jj + 3) * LDW + t] = __float_as_uint(i3);
        }
        __syncthreads();

        // phase A: 16 threads per row, each scans 16 ascending-p columns
        {
            const int r = t & 15;
            const int s = t >> 4;
            if (r < nr) {
                const unsigned int* row = s_iou + r * LDW + s * 16;
                unsigned int bb = row[0];
                int bi = 0;
                #pragma unroll
                for (int i = 1; i < 16; ++i) {
                    unsigned int v = row[i];
                    if (v > bb) { bb = v; bi = i; }   // strict > = min p
                }
                int pw = blockIdx.x * 256 + s * 16 + bi;
                s_part[jc + r][s] = ((unsigned long long)bb << 32) |
                                    (unsigned int)(~pw);
            }
        }
        __syncthreads();   // s_iou reusable next chunk; s_part visible
    }

    // phase B: merge 16 segment partials per gt; plain store (or atomic)
    if (t < NN) {
        unsigned long long best = s_part[t][0];
        #pragma unroll
        for (int s = 1; s < 16; ++s) {
            unsigned long long k = s_part[t][s];
            if (k > best) best = k;                   // ~p breaks iou ties
        }
        if (USE_PART) {
            red[((size_t)b * NBX + blockIdx.x) * NN + t] = best;
        } else {
            atomicMax(&red[b * NN + t], best);
        }
    }
    if (valid) {
        m8[b * PP + p] =
            (unsigned char)(best_j | ((best_ov < 0.5f) ? 0x80 : 0));
    }
}

// -------------------------------------------------------------------------
// Kernel 2: reduce the 35 per-block row keys (USE_PART) or read gkey,
// scatter forced matches into LDS (max j = last-write-wins, matching the
// reference scatter), then encode.
// -------------------------------------------------------------------------
template <bool USE_PART>
__global__ __launch_bounds__(256) void k_encode(
    const float* __restrict__ gt,        // [B,N,4]
    const int*   __restrict__ labels,    // [B,N]
    const float* __restrict__ priors,    // [P,4]
    const unsigned long long* __restrict__ red,   // part or gkey
    const unsigned char* __restrict__ m8,         // [B,P]
    float* __restrict__ loc_out,         // [B,P,4]
    float* __restrict__ conf_out)        // [B,P]
{
    __shared__ int s_forced[256];        // local p -> forced gt j (-1 none)

    const int b = blockIdx.y;
    const int t = threadIdx.x;
    const int p = blockIdx.x * 256 + t;

    s_forced[t] = -1;
    __syncthreads();
    if (t < NN) {
        unsigned long long best;
        if (USE_PART) {
            const unsigned long long* q = red + (size_t)b * NBX * NN + t;
            best = q[0];
            #pragma unroll 5
            for (int bx = 1; bx < NBX; ++bx) {
                unsigned long long k = q[(size_t)bx * NN];
                if (k > best) best = k;
            }
        } else {
            best = red[b * NN + t];
        }
        int kp = (int)~(unsigned int)(best & 0xFFFFFFFFull);
        int lp = kp - blockIdx.x * 256;
        if ((unsigned)lp < 256u) atomicMax(&s_forced[lp], t);
    }
    __syncthreads();

    if (p >= PP) return;
    const int forced_j = s_forced[t];

    const unsigned char m = m8[b * PP + p];
    const int j    = (forced_j >= 0) ? forced_j : (m & 0x7f);
    const int lab  = labels[b * NN + j];
    const int conf = (forced_j < 0 && (m & 0x80)) ? 0 : (lab + 1);

    const float4 pr = reinterpret_cast<const float4*>(priors)[p];
    const float4 g  = reinterpret_cast<const float4*>(gt)[b * NN + j];
    const float mcx = (g.x + g.z) * 0.5f;
    const float mcy = (g.y + g.w) * 0.5f;
    const float mw  = fmaxf(g.z - g.x, 1e-6f);
    const float mh  = fmaxf(g.w - g.y, 1e-6f);
    const float gcx = (mcx - pr.x) / (0.1f * pr.z);
    const float gcy = (mcy - pr.y) / (0.1f * pr.w);
    const float gw  = logf(mw / pr.z) / 0.2f;
    const float gh  = logf(mh / pr.w) / 0.2f;

    reinterpret_cast<float4*>(loc_out)[b * PP + p] =
        make_float4(gcx, gcy, gw, gh);
    conf_out[b * PP + p] = (float)conf;
}

extern "C" void kernel_launch(void* const* d_in, const int* in_sizes, int n_in,
                              void* d_out, int out_size, void* d_ws, size_t ws_size,
                              hipStream_t stream) {
    const float* gt     = (const float*)d_in[0];  // [32,100,4] f32
    const int*   labels = (const int*)  d_in[1];  // [32,100] i32
    const float* priors = (const float*)d_in[2];  // [8732,4] f32

    float* loc  = (float*)d_out;                         // [32,8732,4]
    float* conf = (float*)d_out + (size_t)BB * PP * 4;   // [32,8732]

    const size_t part_bytes = (size_t)BB * NBX * NN * 8;   // 896,000
    const size_t m8_bytes   = (size_t)BB * PP;             // 279,424
    dim3 grid(NBX, BB);

    if (ws_size >= part_bytes + m8_bytes) {
        // atomic-free path: per-block partial keys, no memset dispatch
        unsigned long long* part = (unsigned long long*)d_ws;
        unsigned char* m8 = (unsigned char*)d_ws + part_bytes;
        k_iou_pass<true><<<grid, 256, 0, stream>>>(gt, priors, part, m8);
        k_encode<true><<<grid, 256, 0, stream>>>(gt, labels, priors, part,
                                                 m8, loc, conf);
    } else {
        // fallback: gkey + atomicMax (needs zeroed keys)
        unsigned long long* gkey = (unsigned long long*)d_ws;        // [32,100]
        unsigned char* m8 = (unsigned char*)d_ws + (size_t)BB * NN * 8;
        hipMemsetAsync(gkey, 0, (size_t)BB * NN * 8, stream);
        k_iou_pass<false><<<grid, 256, 0, stream>>>(gt, priors, gkey, m8);
        k_encode<false><<<grid, 256, 0, stream>>>(gt, labels, priors, gkey,
                                                  m8, loc, conf);
    }
}